// Round 13
// baseline (88.414 us; speedup 1.0000x reference)
//
#include <hip/hip_runtime.h>
#include <hip/hip_bf16.h>

#define WB 8192
#define WD 128
#define WC 100
#define NSPLIT 32
#define JSPL (WB/NSPLIT)   // 256 j per split
#define NTT (JSPL/16)      // 16 j-steps of 16 rows

typedef __attribute__((ext_vector_type(8))) short short8v;
typedef __attribute__((ext_vector_type(4))) float float4v;

#define SQS 3.798282f                 // sqrt((1/TAU)/ln2): fold scale into bf16 z
#define LN2F 0.69314718055994531f

#define EXP2(x) __builtin_amdgcn_exp2f(x)
#define LOG2(x) __builtin_amdgcn_logf(x)

// ---- workspace layout (bytes) ----
#define WS_ZBF   0u          // bf16 z (pre-scaled): 2097152
#define WS_S     2097152u    // S[100][128] f32 = 51200    (memset region start)
#define WS_CNT   2148352u    // cnt[128] int = 512
#define WS_ACC   2148864u    // accf, accn, ticket, pad = 16 (memset region end)
#define WS_PM    2148992u    // partM[32][8192] f32 = 1048576
#define WS_PL    3197568u    // partL[32][8192] f32 = 1048576 (end 4246144)

__device__ __forceinline__ unsigned short f2bf(float x){
  unsigned u = __float_as_uint(x);
  u += 0x7fffu + ((u>>16)&1u);      // RNE
  return (unsigned short)(u>>16);
}

// blocks 0..511: convert+prescale z->bf16; 512..767: class sums (32 rows each)
__global__ __launch_bounds__(256) void k_prep(const float* __restrict__ z,
                                              const int* __restrict__ labels,
                                              unsigned short* __restrict__ zbf,
                                              float* __restrict__ S,
                                              int* __restrict__ cnt){
  __shared__ float sacc[WC*WD];
  __shared__ int slab[32];
  __shared__ int slcnt[WC];
  const int bid = blockIdx.x, t = threadIdx.x;
  if (bid < 512){
    int idx = bid*256 + t;
    const float4* zi = (const float4*)z;
    float4 a = zi[idx*2], b = zi[idx*2+1];
    uint4 o;
    o.x = (unsigned)f2bf(a.x*SQS) | ((unsigned)f2bf(a.y*SQS)<<16);
    o.y = (unsigned)f2bf(a.z*SQS) | ((unsigned)f2bf(a.w*SQS)<<16);
    o.z = (unsigned)f2bf(b.x*SQS) | ((unsigned)f2bf(b.y*SQS)<<16);
    o.w = (unsigned)f2bf(b.z*SQS) | ((unsigned)f2bf(b.w*SQS)<<16);
    ((uint4*)zbf)[idx] = o;
    return;
  }
  const int cb = bid - 512;           // 256 csum blocks x 32 rows
  const int rowBase = cb*32;
  for (int i = t; i < WC*WD; i += 256) sacc[i] = 0.f;
  if (t < WC) slcnt[t] = 0;
  if (t < 32) slab[t] = labels[rowBase + t];
  __syncthreads();
  const int col = t & 127, half = t >> 7;
  #pragma unroll 4
  for (int r = 0; r < 16; r++){
    int row = r*2 + half;
    atomicAdd(&sacc[slab[row]*WD + col], z[(size_t)(rowBase+row)*WD + col]);
  }
  if (t < 32) atomicAdd(&slcnt[slab[t]], 1);
  __syncthreads();
  for (int i = t; i < WC*WD; i += 256){
    if (slcnt[i>>7] > 0) atomicAdd(&S[i], sacc[i]);
  }
  if (t < WC && slcnt[t] > 0) atomicAdd(&cnt[t], slcnt[t]);
}

// pure-LSE wave body: no labels, no pos-sum, defer-max online softmax.
template<bool DIAG>
__device__ __forceinline__ void lse_wave(const unsigned short* __restrict__ zbf,
                                         int awave, int split, int lane,
                                         float* __restrict__ partM,
                                         float* __restrict__ partL){
  const int j0 = split*JSPL;
  const int lg = lane>>4, ln = lane&15;

  // anchor B-fragments: B[k][n]; lane: n=ln, k=kk*32+lg*8+e
  short8v bf[4][4];
  #pragma unroll
  for (int ss = 0; ss < 4; ss++){
    const unsigned short* zr = zbf + (size_t)(awave + ss*16 + ln)*WD;
    #pragma unroll
    for (int kk = 0; kk < 4; kk++)
      bf[ss][kk] = *(const short8v*)(zr + kk*32 + lg*8);
  }

  float m[4], l[4];
  #pragma unroll
  for (int ss = 0; ss < 4; ss++){ m[ss] = -INFINITY; l[ss] = 0.f; }

  const unsigned short* ap = zbf + (size_t)(j0+ln)*WD + lg*8;
  short8v afA[4], afB[4];
#define LOADA(dst, tt) { const unsigned short* p_ = ap + (size_t)(tt)*16*WD; \
    dst[0] = *(const short8v*)(p_);      dst[1] = *(const short8v*)(p_+32);  \
    dst[2] = *(const short8v*)(p_+64);   dst[3] = *(const short8v*)(p_+96); }

#define COMPUTE(af, tt) { \
    const int jb = j0 + (tt)*16; \
    _Pragma("unroll") \
    for (int ss = 0; ss < 4; ss++){ \
      float4v acc = {0.f,0.f,0.f,0.f}; \
      _Pragma("unroll") \
      for (int kk = 0; kk < 4; kk++) \
        acc = __builtin_amdgcn_mfma_f32_16x16x32_bf16(af[kk], bf[ss][kk], acc, 0,0,0); \
      float v0 = acc[0], v1 = acc[1], v2 = acc[2], v3 = acc[3]; \
      if (DIAG){ \
        if (jb == awave + ss*16){ \
          const int r0 = lg*4; \
          if (r0+0 == ln) v0 = -INFINITY; \
          if (r0+1 == ln) v1 = -INFINITY; \
          if (r0+2 == ln) v2 = -INFINITY; \
          if (r0+3 == ln) v3 = -INFINITY; \
        } \
      } \
      float tmax = fmaxf(fmaxf(v0,v1), fmaxf(v2,v3)); \
      if (__any(tmax > m[ss] + 8.0f)){ \
        float mn = fmaxf(m[ss], tmax); \
        l[ss] *= EXP2(m[ss]-mn); \
        m[ss] = mn; \
      } \
      l[ss] += (EXP2(v0-m[ss]) + EXP2(v1-m[ss])) \
             + (EXP2(v2-m[ss]) + EXP2(v3-m[ss])); \
    } }

  LOADA(afA, 0); LOADA(afB, 1);
  for (int tt = 0; tt < NTT; tt += 2){
    COMPUTE(afA, tt);
    if (tt+2 < NTT) LOADA(afA, tt+2);
    COMPUTE(afB, tt+1);
    if (tt+3 < NTT) LOADA(afB, tt+3);
  }
#undef LOADA
#undef COMPUTE

  // combine lanes {x^16, x^32} (same anchor, different j-row groups)
  #pragma unroll
  for (int ss = 0; ss < 4; ss++){
    float mm = m[ss], ll = l[ss];
    #pragma unroll
    for (int off = 16; off < 64; off <<= 1){
      float mo = __shfl_xor(mm, off);
      float lo = __shfl_xor(ll, off);
      float M = fmaxf(mm, mo);
      ll = ll*EXP2(mm-M) + lo*EXP2(mo-M);
      mm = M;
    }
    if (lane < 16){
      size_t o = (size_t)split*WB + awave + ss*16 + lane;
      partM[o] = mm; partL[o] = ll;
    }
  }
}

// 4096 one-wave blocks: xcd=bid&7 owns 4 splits; 16 blocks/CU for residency.
__global__ __launch_bounds__(64) void k_lse(const unsigned short* __restrict__ zbf,
                                            float* __restrict__ partM,
                                            float* __restrict__ partL){
  const int lane = threadIdx.x;
  const int bid = blockIdx.x;
  const int xcd = bid & 7, k2 = bid >> 3;            // k2 0..511
  const int split = (xcd<<2) | (k2 & 3);             // 0..31
  const int awave = (k2>>2)*64;                      // 0..8128
  if ((awave >> 8) == split)
    lse_wave<true >(zbf, awave, split, lane, partM, partL);
  else
    lse_wave<false>(zbf, awave, split, lane, partM, partL);
}

// 32 blocks x 256 threads: one anchor per thread; pos term from S-table.
__global__ __launch_bounds__(256) void k_final(const float* __restrict__ z,
                                               const int* __restrict__ labels,
                                               const float* __restrict__ S,
                                               const int* __restrict__ cnt,
                                               const float* __restrict__ partM,
                                               const float* __restrict__ partL,
                                               float* accf, int* accn, int* ticket,
                                               float* __restrict__ out){
  const int t = threadIdx.x;
  const int a = blockIdx.x*256 + t;
  float mm = -INFINITY;
  #pragma unroll 8
  for (int sp = 0; sp < NSPLIT; sp++)
    mm = fmaxf(mm, partM[(size_t)sp*WB + a]);
  float ll = 0.f;
  #pragma unroll 8
  for (int sp = 0; sp < NSPLIT; sp++)
    ll = fmaf(partL[(size_t)sp*WB + a], EXP2(partM[(size_t)sp*WB + a] - mm), ll);
  float lse = (mm + LOG2(ll)) * LN2F;     // natural-log LSE
  int lab = labels[a];
  const float4* zi = (const float4*)(z + (size_t)a*WD);
  const float4* sc = (const float4*)(S + (size_t)lab*WD);
  float pd = 0.f, sd = 0.f;
  #pragma unroll 8
  for (int k = 0; k < WD/4; k++){
    float4 va = zi[k], vb = sc[k];
    pd += va.x*vb.x + va.y*vb.y + va.z*vb.z + va.w*vb.w;
    sd += va.x*va.x + va.y*va.y + va.z*va.z + va.w*va.w;
  }
  int np = cnt[lab] - 1;
  float loss = 0.f, val = 0.f;
  if (np > 0){ loss = lse - (pd - sd)*10.0f/(float)np; val = 1.f; }
  #pragma unroll
  for (int off = 32; off > 0; off >>= 1){
    loss += __shfl_down(loss, off);
    val  += __shfl_down(val,  off);
  }
  __shared__ float sl[4], sv[4];
  int wv = t>>6, lane = t&63;
  if (lane == 0){ sl[wv] = loss; sv[wv] = val; }
  __syncthreads();
  if (t == 0){
    atomicAdd(accf, sl[0]+sl[1]+sl[2]+sl[3]);
    atomicAdd(accn, (int)(sv[0]+sv[1]+sv[2]+sv[3] + 0.5f));
    __threadfence();
    int tk = atomicAdd(ticket, 1);
    if (tk == 31){                         // last block finalizes
      float f = atomicAdd(accf, 0.f);
      int   n = atomicAdd(accn, 0);
      out[0] = f / (float)max(n, 1);
    }
  }
}

extern "C" void kernel_launch(void* const* d_in, const int* in_sizes, int n_in,
                              void* d_out, int out_size, void* d_ws, size_t ws_size,
                              hipStream_t stream){
  const float* z = (const float*)d_in[0];
  const int* labels = (const int*)d_in[1];
  char* ws = (char*)d_ws;
  unsigned short* zbf = (unsigned short*)(ws + WS_ZBF);
  float* S      = (float*)(ws + WS_S);
  int*   cnt    = (int*)(ws + WS_CNT);
  float* accf   = (float*)(ws + WS_ACC);
  int*   accn   = (int*)(ws + WS_ACC + 4);
  int*   ticket = (int*)(ws + WS_ACC + 8);
  float* partM  = (float*)(ws + WS_PM);
  float* partL  = (float*)(ws + WS_PL);
  float* out = (float*)d_out;

  // zero S + cnt + acc/ticket in one contiguous async memset
  hipMemsetAsync(ws + WS_S, 0, (WS_ACC + 16) - WS_S, stream);
  hipLaunchKernelGGL(k_prep,  dim3(512 + 256), dim3(256), 0, stream,
                     z, labels, zbf, S, cnt);
  hipLaunchKernelGGL(k_lse,   dim3(4096),      dim3(64),  0, stream,
                     zbf, partM, partL);
  hipLaunchKernelGGL(k_final, dim3(32),        dim3(256), 0, stream,
                     z, labels, S, cnt, partM, partL, accf, accn, ticket, out);
}

// Round 14
// 66.227 us; speedup vs baseline: 1.3350x; 1.3350x over previous
//
#include <hip/hip_runtime.h>
#include <hip/hip_bf16.h>

#define WB 8192
#define WD 128
#define WC 100
#define NSPLIT 16
#define JSPL (WB/NSPLIT)   // 512 j per split
#define NTT (JSPL/16)      // 32 j-steps of 16 rows

typedef __attribute__((ext_vector_type(8))) short short8v;
typedef __attribute__((ext_vector_type(4))) float float4v;

#define SQS 3.798282f                 // sqrt((1/TAU)/ln2): fold scale into bf16 z
#define LN2F 0.69314718055994531f

#define EXP2(x) __builtin_amdgcn_exp2f(x)
#define LOG2(x) __builtin_amdgcn_logf(x)

// ---- workspace layout (bytes) ----
#define WS_ZBF   0u          // bf16 z (pre-scaled): 2097152
#define WS_CNT   2097152u    // cnt[128] int = 512          (memset: CNT..ACC+16)
#define WS_ACC   2097664u    // accf, accn, ticket, pad = 16
#define WS_LAB   2097680u    // labu8[8192] = 8192
#define WS_PM    2105872u    // partM[16][8192] f32 = 524288
#define WS_PL    2630160u    // partL[16][8192] f32 = 524288
#define WS_PP    3154448u    // partPS[16][8192] f32 = 524288 (end 3678736)

__device__ __forceinline__ unsigned short f2bf(float x){
  unsigned u = __float_as_uint(x);
  u += 0x7fffu + ((u>>16)&1u);      // RNE
  return (unsigned short)(u>>16);
}

// blocks 0..511: convert+prescale z->bf16; 512..519: labels->u8 + histogram
__global__ __launch_bounds__(256) void k_prep(const float* __restrict__ z,
                                              const int* __restrict__ labels,
                                              unsigned short* __restrict__ zbf,
                                              unsigned* __restrict__ labu8,
                                              int* __restrict__ cnt){
  const int bid = blockIdx.x, t = threadIdx.x;
  if (bid < 512){
    int idx = bid*256 + t;
    const float4* zi = (const float4*)z;
    float4 a = zi[idx*2], b = zi[idx*2+1];
    uint4 o;
    o.x = (unsigned)f2bf(a.x*SQS) | ((unsigned)f2bf(a.y*SQS)<<16);
    o.y = (unsigned)f2bf(a.z*SQS) | ((unsigned)f2bf(a.w*SQS)<<16);
    o.z = (unsigned)f2bf(b.x*SQS) | ((unsigned)f2bf(b.y*SQS)<<16);
    o.w = (unsigned)f2bf(b.z*SQS) | ((unsigned)f2bf(b.w*SQS)<<16);
    ((uint4*)zbf)[idx] = o;
    return;
  }
  __shared__ int hist[128];
  const int cb = bid - 512;              // 8 blocks x 1024 labels
  if (t < 128) hist[t] = 0;
  __syncthreads();
  {  // pack 4 labels -> u32, and histogram
    int i = cb*1024 + t*4;
    int4 l4 = *(const int4*)(labels + i);
    labu8[cb*256 + t] = (unsigned)l4.x | ((unsigned)l4.y<<8)
                      | ((unsigned)l4.z<<16) | ((unsigned)l4.w<<24);
    atomicAdd(&hist[l4.x], 1); atomicAdd(&hist[l4.y], 1);
    atomicAdd(&hist[l4.z], 1); atomicAdd(&hist[l4.w], 1);
  }
  __syncthreads();
  if (t < 128 && hist[t] > 0) atomicAdd(&cnt[t], hist[t]);
}

template<bool DIAG>
__device__ __forceinline__ void lse_wave(const unsigned short* __restrict__ zbf,
                                         const unsigned* __restrict__ ldslab,
                                         const int* __restrict__ labels,
                                         int awave, int split, int lane,
                                         float* __restrict__ partM,
                                         float* __restrict__ partL,
                                         float* __restrict__ partPS){
  const int j0 = split*JSPL;
  const int lg = lane>>4, ln = lane&15;

  // anchor B-fragments: B[k][n]; lane: n=ln, k=kk*32+lg*8+e
  short8v bf[4][4];
  int labA[4];
  #pragma unroll
  for (int ss = 0; ss < 4; ss++){
    const unsigned short* zr = zbf + (size_t)(awave + ss*16 + ln)*WD;
    #pragma unroll
    for (int kk = 0; kk < 4; kk++)
      bf[ss][kk] = *(const short8v*)(zr + kk*32 + lg*8);
    labA[ss] = labels[awave + ss*16 + ln];
  }

  float m[4], l[4], ps[4];
  #pragma unroll
  for (int ss = 0; ss < 4; ss++){ m[ss] = -INFINITY; l[ss] = 0.f; ps[ss] = 0.f; }

  const unsigned short* ap = zbf + (size_t)(j0+ln)*WD + lg*8;
  short8v af0[4], af1[4], af2[4], af3[4];
#define LOADA(dst, tt) { const unsigned short* p_ = ap + (size_t)(tt)*16*WD; \
    dst[0] = *(const short8v*)(p_);      dst[1] = *(const short8v*)(p_+32);  \
    dst[2] = *(const short8v*)(p_+64);   dst[3] = *(const short8v*)(p_+96); }

#define COMPUTE(af, tt, lw) { \
    const int jb = j0 + (tt)*16; \
    const int b0 = (int)((lw)&255u),       b1 = (int)(((lw)>>8)&255u); \
    const int b2 = (int)(((lw)>>16)&255u), b3 = (int)((lw)>>24); \
    _Pragma("unroll") \
    for (int ss = 0; ss < 4; ss++){ \
      float4v acc = {0.f,0.f,0.f,0.f}; \
      _Pragma("unroll") \
      for (int kk = 0; kk < 4; kk++) \
        acc = __builtin_amdgcn_mfma_f32_16x16x32_bf16(af[kk], bf[ss][kk], acc, 0,0,0); \
      float v0 = acc[0], v1 = acc[1], v2 = acc[2], v3 = acc[3]; \
      if (DIAG){ \
        const bool dq = (jb == awave + ss*16); \
        const int r0 = lg*4; \
        ps[ss] += (((b0==labA[ss]) && !(dq&&(r0+0==ln))) ? v0 : 0.f) \
                + (((b1==labA[ss]) && !(dq&&(r0+1==ln))) ? v1 : 0.f) \
                + (((b2==labA[ss]) && !(dq&&(r0+2==ln))) ? v2 : 0.f) \
                + (((b3==labA[ss]) && !(dq&&(r0+3==ln))) ? v3 : 0.f); \
        if (dq){ \
          if (r0+0 == ln) v0 = -INFINITY; \
          if (r0+1 == ln) v1 = -INFINITY; \
          if (r0+2 == ln) v2 = -INFINITY; \
          if (r0+3 == ln) v3 = -INFINITY; \
        } \
      } else { \
        ps[ss] += ((b0==labA[ss]) ? v0 : 0.f) + ((b1==labA[ss]) ? v1 : 0.f) \
                + ((b2==labA[ss]) ? v2 : 0.f) + ((b3==labA[ss]) ? v3 : 0.f); \
      } \
      float tmax = fmaxf(fmaxf(v0,v1), fmaxf(v2,v3)); \
      float mn = fmaxf(m[ss], tmax); \
      l[ss] = l[ss]*EXP2(m[ss]-mn) \
            + ((EXP2(v0-mn) + EXP2(v1-mn)) + (EXP2(v2-mn) + EXP2(v3-mn))); \
      m[ss] = mn; \
    } }

  unsigned lw0 = ldslab[0*4 + lg];
  unsigned lw1 = ldslab[1*4 + lg];
  unsigned lw2 = ldslab[2*4 + lg];
  unsigned lw3 = ldslab[3*4 + lg];
  LOADA(af0, 0); LOADA(af1, 1); LOADA(af2, 2); LOADA(af3, 3);
  for (int tt = 0; tt < NTT; tt += 4){
    COMPUTE(af0, tt, lw0);
    if (tt+4 < NTT){ LOADA(af0, tt+4); lw0 = ldslab[(tt+4)*4 + lg]; }
    COMPUTE(af1, tt+1, lw1);
    if (tt+5 < NTT){ LOADA(af1, tt+5); lw1 = ldslab[(tt+5)*4 + lg]; }
    COMPUTE(af2, tt+2, lw2);
    if (tt+6 < NTT){ LOADA(af2, tt+6); lw2 = ldslab[(tt+6)*4 + lg]; }
    COMPUTE(af3, tt+3, lw3);
    if (tt+7 < NTT){ LOADA(af3, tt+7); lw3 = ldslab[(tt+7)*4 + lg]; }
  }
#undef LOADA
#undef COMPUTE

  // combine lanes {x^16, x^32} (same anchor, different j-row groups)
  #pragma unroll
  for (int ss = 0; ss < 4; ss++){
    float mm = m[ss], ll = l[ss], pp = ps[ss];
    #pragma unroll
    for (int off = 16; off < 64; off <<= 1){
      float mo = __shfl_xor(mm, off);
      float lo = __shfl_xor(ll, off);
      float M = fmaxf(mm, mo);
      ll = ll*EXP2(mm-M) + lo*EXP2(mo-M);
      mm = M;
      pp += __shfl_xor(pp, off);
    }
    if (lane < 16){
      size_t o = (size_t)split*WB + awave + ss*16 + lane;
      partM[o] = mm; partL[o] = ll; partPS[o] = pp;
    }
  }
}

// 512 blocks x 256 (4 waves). All 4 waves share one split; each wave owns 64 anchors.
__global__ __launch_bounds__(256) void k_lse(const unsigned short* __restrict__ zbf,
                                             const int* __restrict__ labels,
                                             const unsigned* __restrict__ labu8,
                                             float* __restrict__ partM,
                                             float* __restrict__ partL,
                                             float* __restrict__ partPS){
  __shared__ unsigned ldslab[JSPL/4];      // 128 words = this split's 512 labels
  const int t = threadIdx.x, wv = t>>6, lane = t&63;
  const int bid = blockIdx.x;
  const int xcd = bid & 7, chunk = bid >> 3;
  const int split = (xcd<<1) | (chunk & 1);          // XCD owns 2 j-windows
  const int ablk  = ((chunk>>1)<<2) | wv;            // 0..127
  const int awave = ablk*64;
  const int j0 = split*JSPL;

  if (t < JSPL/4) ldslab[t] = labu8[(j0>>2) + t];
  __syncthreads();

  if ((awave >> 9) == split)
    lse_wave<true >(zbf, ldslab, labels, awave, split, lane, partM, partL, partPS);
  else
    lse_wave<false>(zbf, ldslab, labels, awave, split, lane, partM, partL, partPS);
}

// 32 blocks x 256 threads: one anchor per thread.
__global__ __launch_bounds__(256) void k_final(const int* __restrict__ labels,
                                               const int* __restrict__ cnt,
                                               const float* __restrict__ partM,
                                               const float* __restrict__ partL,
                                               const float* __restrict__ partPS,
                                               float* accf, int* accn, int* ticket,
                                               float* __restrict__ out){
  const int t = threadIdx.x;
  const int a = blockIdx.x*256 + t;
  float mm = -INFINITY;
  #pragma unroll 8
  for (int sp = 0; sp < NSPLIT; sp++)
    mm = fmaxf(mm, partM[(size_t)sp*WB + a]);
  float ll = 0.f, pp = 0.f;
  #pragma unroll 8
  for (int sp = 0; sp < NSPLIT; sp++){
    ll = fmaf(partL[(size_t)sp*WB + a], EXP2(partM[(size_t)sp*WB + a] - mm), ll);
    pp += partPS[(size_t)sp*WB + a];
  }
  float lse2 = mm + LOG2(ll);             // log2 units
  int lab = labels[a];
  int np = cnt[lab] - 1;
  float loss = 0.f, val = 0.f;
  if (np > 0){ loss = LN2F*(lse2 - pp/(float)np); val = 1.f; }
  #pragma unroll
  for (int off = 32; off > 0; off >>= 1){
    loss += __shfl_down(loss, off);
    val  += __shfl_down(val,  off);
  }
  __shared__ float sl[4], sv[4];
  int wv = t>>6, lane = t&63;
  if (lane == 0){ sl[wv] = loss; sv[wv] = val; }
  __syncthreads();
  if (t == 0){
    atomicAdd(accf, sl[0]+sl[1]+sl[2]+sl[3]);
    atomicAdd(accn, (int)(sv[0]+sv[1]+sv[2]+sv[3] + 0.5f));
    __threadfence();
    int tk = atomicAdd(ticket, 1);
    if (tk == 31){                         // last block finalizes
      float f = atomicAdd(accf, 0.f);
      int   n = atomicAdd(accn, 0);
      out[0] = f / (float)max(n, 1);
    }
  }
}

extern "C" void kernel_launch(void* const* d_in, const int* in_sizes, int n_in,
                              void* d_out, int out_size, void* d_ws, size_t ws_size,
                              hipStream_t stream){
  const float* z = (const float*)d_in[0];
  const int* labels = (const int*)d_in[1];
  char* ws = (char*)d_ws;
  unsigned short* zbf = (unsigned short*)(ws + WS_ZBF);
  int*      cnt    = (int*)(ws + WS_CNT);
  float*    accf   = (float*)(ws + WS_ACC);
  int*      accn   = (int*)(ws + WS_ACC + 4);
  int*      ticket = (int*)(ws + WS_ACC + 8);
  unsigned* labu8  = (unsigned*)(ws + WS_LAB);
  float*    partM  = (float*)(ws + WS_PM);
  float*    partL  = (float*)(ws + WS_PL);
  float*    partPS = (float*)(ws + WS_PP);
  float* out = (float*)d_out;

  hipMemsetAsync(ws + WS_CNT, 0, 512 + 16, stream);   // cnt + acc/ticket
  hipLaunchKernelGGL(k_prep,  dim3(520), dim3(256), 0, stream,
                     z, labels, zbf, labu8, cnt);
  hipLaunchKernelGGL(k_lse,   dim3(512), dim3(256), 0, stream,
                     zbf, labels, labu8, partM, partL, partPS);
  hipLaunchKernelGGL(k_final, dim3(32),  dim3(256), 0, stream,
                     labels, cnt, partM, partL, partPS, accf, accn, ticket, out);
}

// Round 15
// 54.138 us; speedup vs baseline: 1.6331x; 1.2233x over previous
//
#include <hip/hip_runtime.h>
#include <hip/hip_bf16.h>

#define WB 8192
#define WD 128
#define WC 100
#define NSPLIT 16
#define JSPL (WB/NSPLIT)   // 512 j per split
#define NTT (JSPL/16)      // 32 j-steps of 16 rows
#define NPH (NTT/4)        // 8 phases of 4 steps (64 rows)
#define PITCH 272          // 256B row + 16B pad (bank decorrelation)

typedef __attribute__((ext_vector_type(8))) short short8v;
typedef __attribute__((ext_vector_type(4))) float float4v;

#define SQS 3.798282f                 // sqrt((1/TAU)/ln2): fold scale into bf16 z
#define LN2F 0.69314718055994531f

#define EXP2(x) __builtin_amdgcn_exp2f(x)
#define LOG2(x) __builtin_amdgcn_logf(x)

// ---- workspace layout (bytes) ----
#define WS_ZBF   0u          // bf16 z (pre-scaled): 2097152
#define WS_CNT   2097152u    // cnt[128] int = 512          (memset: CNT..ACC+16)
#define WS_ACC   2097664u    // accf, accn, ticket, pad = 16
#define WS_LAB   2097680u    // labu8[8192] = 8192
#define WS_PM    2105872u    // partM[16][8192] f32 = 524288
#define WS_PL    2630160u    // partL[16][8192] f32 = 524288
#define WS_PP    3154448u    // partPS[16][8192] f32 = 524288 (end 3678736)

__device__ __forceinline__ unsigned short f2bf(float x){
  unsigned u = __float_as_uint(x);
  u += 0x7fffu + ((u>>16)&1u);      // RNE
  return (unsigned short)(u>>16);
}

// blocks 0..511: convert+prescale z->bf16; 512..519: labels->u8 + histogram
__global__ __launch_bounds__(256) void k_prep(const float* __restrict__ z,
                                              const int* __restrict__ labels,
                                              unsigned short* __restrict__ zbf,
                                              unsigned* __restrict__ labu8,
                                              int* __restrict__ cnt){
  const int bid = blockIdx.x, t = threadIdx.x;
  if (bid < 512){
    int idx = bid*256 + t;
    const float4* zi = (const float4*)z;
    float4 a = zi[idx*2], b = zi[idx*2+1];
    uint4 o;
    o.x = (unsigned)f2bf(a.x*SQS) | ((unsigned)f2bf(a.y*SQS)<<16);
    o.y = (unsigned)f2bf(a.z*SQS) | ((unsigned)f2bf(a.w*SQS)<<16);
    o.z = (unsigned)f2bf(b.x*SQS) | ((unsigned)f2bf(b.y*SQS)<<16);
    o.w = (unsigned)f2bf(b.z*SQS) | ((unsigned)f2bf(b.w*SQS)<<16);
    ((uint4*)zbf)[idx] = o;
    return;
  }
  __shared__ int hist[128];
  const int cb = bid - 512;              // 8 blocks x 1024 labels
  if (t < 128) hist[t] = 0;
  __syncthreads();
  {  // pack 4 labels -> u32, and histogram
    int i = cb*1024 + t*4;
    int4 l4 = *(const int4*)(labels + i);
    labu8[cb*256 + t] = (unsigned)l4.x | ((unsigned)l4.y<<8)
                      | ((unsigned)l4.z<<16) | ((unsigned)l4.w<<24);
    atomicAdd(&hist[l4.x], 1); atomicAdd(&hist[l4.y], 1);
    atomicAdd(&hist[l4.z], 1); atomicAdd(&hist[l4.w], 1);
  }
  __syncthreads();
  if (t < 128 && hist[t] > 0) atomicAdd(&cnt[t], hist[t]);
}

// 512 blocks x 256 (4 waves). Block shares one split; A-tile staged once per
// block into LDS in 64-row double-buffered phases (4x VMEM cut vs per-wave).
__global__ __launch_bounds__(256) void k_lse(const unsigned short* __restrict__ zbf,
                                             const int* __restrict__ labels,
                                             const unsigned* __restrict__ labu8,
                                             float* __restrict__ partM,
                                             float* __restrict__ partL,
                                             float* __restrict__ partPS){
  __shared__ __align__(16) unsigned char atile[2][64*PITCH];  // 2 x 17 KB
  __shared__ unsigned ldslab[JSPL/4];      // 128 words = this split's 512 labels
  const int t = threadIdx.x, wv = t>>6, lane = t&63;
  const int bid = blockIdx.x;
  const int xcd = bid & 7, chunk = bid >> 3;
  const int split = (xcd<<1) | (chunk & 1);          // XCD owns 2 j-windows
  const int ablk  = ((chunk>>1)<<2) | wv;            // 0..127
  const int awave = ablk*64;
  const int j0 = split*JSPL;
  const int lg = lane>>4, ln = lane&15;
  const bool DIAG = ((awave >> 9) == split);

  if (t < JSPL/4) ldslab[t] = labu8[(j0>>2) + t];

  // anchor B-fragments: B[k][n]; lane: n=ln, k=kk*32+lg*8+e
  short8v bf[4][4];
  int labA[4];
  #pragma unroll
  for (int ss = 0; ss < 4; ss++){
    const unsigned short* zr = zbf + (size_t)(awave + ss*16 + ln)*WD;
    #pragma unroll
    for (int kk = 0; kk < 4; kk++)
      bf[ss][kk] = *(const short8v*)(zr + kk*32 + lg*8);
    labA[ss] = labels[awave + ss*16 + ln];
  }

  float m[4], l[4], ps[4];
  #pragma unroll
  for (int ss = 0; ss < 4; ss++){ m[ss] = -INFINITY; l[ss] = 0.f; ps[ss] = 0.f; }

  // staging: thread t handles row srow0+16q, 16B chunk sck (q=0..3)
  const int srow0 = t>>4, sck = t&15;
  const unsigned short* sb = zbf + (size_t)(j0 + srow0)*WD + sck*8;
  const unsigned swbase = srow0*PITCH + sck*16;

  // prologue: stage phase 0 into buf 0
  {
    uint4 s0 = *(const uint4*)(sb + (size_t)( 0)*WD);
    uint4 s1 = *(const uint4*)(sb + (size_t)(16)*WD);
    uint4 s2 = *(const uint4*)(sb + (size_t)(32)*WD);
    uint4 s3 = *(const uint4*)(sb + (size_t)(48)*WD);
    *(uint4*)&atile[0][swbase +  0*PITCH] = s0;
    *(uint4*)&atile[0][swbase + 16*PITCH] = s1;
    *(uint4*)&atile[0][swbase + 32*PITCH] = s2;
    *(uint4*)&atile[0][swbase + 48*PITCH] = s3;
  }
  __syncthreads();

  for (int ph = 0; ph < NPH; ph++){
    const int cur = ph & 1;
    // T14: issue next phase's global loads NOW; they drain during compute
    uint4 nx0, nx1, nx2, nx3;
    const bool have = (ph+1 < NPH);
    if (have){
      const unsigned short* nb = sb + (size_t)((ph+1)*64)*WD;
      nx0 = *(const uint4*)(nb + (size_t)( 0)*WD);
      nx1 = *(const uint4*)(nb + (size_t)(16)*WD);
      nx2 = *(const uint4*)(nb + (size_t)(32)*WD);
      nx3 = *(const uint4*)(nb + (size_t)(48)*WD);
    }
    #pragma unroll
    for (int s = 0; s < 4; s++){
      const int tt = ph*4 + s;
      const int jb = j0 + tt*16;
      const unsigned lw = ldslab[tt*4 + lg];
      const int b0 = (int)(lw&255u),       b1 = (int)((lw>>8)&255u);
      const int b2 = (int)((lw>>16)&255u), b3 = (int)(lw>>24);
      const int rl = s*16 + ln;
      const unsigned rbase = rl*PITCH + lg*16;
      short8v af0 = *(const short8v*)&atile[cur][rbase +   0];
      short8v af1 = *(const short8v*)&atile[cur][rbase +  64];
      short8v af2 = *(const short8v*)&atile[cur][rbase + 128];
      short8v af3 = *(const short8v*)&atile[cur][rbase + 192];
      #pragma unroll
      for (int ss = 0; ss < 4; ss++){
        float4v acc = {0.f,0.f,0.f,0.f};
        acc = __builtin_amdgcn_mfma_f32_16x16x32_bf16(af0, bf[ss][0], acc, 0,0,0);
        acc = __builtin_amdgcn_mfma_f32_16x16x32_bf16(af1, bf[ss][1], acc, 0,0,0);
        acc = __builtin_amdgcn_mfma_f32_16x16x32_bf16(af2, bf[ss][2], acc, 0,0,0);
        acc = __builtin_amdgcn_mfma_f32_16x16x32_bf16(af3, bf[ss][3], acc, 0,0,0);
        float v0 = acc[0], v1 = acc[1], v2 = acc[2], v3 = acc[3];
        ps[ss] += ((b0==labA[ss]) ? v0 : 0.f) + ((b1==labA[ss]) ? v1 : 0.f)
                + ((b2==labA[ss]) ? v2 : 0.f) + ((b3==labA[ss]) ? v3 : 0.f);
        if (DIAG && jb == awave + ss*16){   // wave-uniform; self always matches
          const int r0 = lg*4;
          if (r0+0 == ln){ ps[ss] -= v0; v0 = -INFINITY; }
          if (r0+1 == ln){ ps[ss] -= v1; v1 = -INFINITY; }
          if (r0+2 == ln){ ps[ss] -= v2; v2 = -INFINITY; }
          if (r0+3 == ln){ ps[ss] -= v3; v3 = -INFINITY; }
        }
        float tmax = fmaxf(fmaxf(v0,v1), fmaxf(v2,v3));
        float mn = fmaxf(m[ss], tmax);
        l[ss] = l[ss]*EXP2(m[ss]-mn)
              + ((EXP2(v0-mn) + EXP2(v1-mn)) + (EXP2(v2-mn) + EXP2(v3-mn)));
        m[ss] = mn;
      }
    }
    if (have){
      *(uint4*)&atile[cur^1][swbase +  0*PITCH] = nx0;
      *(uint4*)&atile[cur^1][swbase + 16*PITCH] = nx1;
      *(uint4*)&atile[cur^1][swbase + 32*PITCH] = nx2;
      *(uint4*)&atile[cur^1][swbase + 48*PITCH] = nx3;
    }
    __syncthreads();
  }

  // combine lanes {x^16, x^32} (same anchor, different j-row groups)
  #pragma unroll
  for (int ss = 0; ss < 4; ss++){
    float mm = m[ss], ll = l[ss], pp = ps[ss];
    #pragma unroll
    for (int off = 16; off < 64; off <<= 1){
      float mo = __shfl_xor(mm, off);
      float lo = __shfl_xor(ll, off);
      float M = fmaxf(mm, mo);
      ll = ll*EXP2(mm-M) + lo*EXP2(mo-M);
      mm = M;
      pp += __shfl_xor(pp, off);
    }
    if (lane < 16){
      size_t o = (size_t)split*WB + awave + ss*16 + lane;
      partM[o] = mm; partL[o] = ll; partPS[o] = pp;
    }
  }
}

// 32 blocks x 256 threads: one anchor per thread.
__global__ __launch_bounds__(256) void k_final(const int* __restrict__ labels,
                                               const int* __restrict__ cnt,
                                               const float* __restrict__ partM,
                                               const float* __restrict__ partL,
                                               const float* __restrict__ partPS,
                                               float* accf, int* accn, int* ticket,
                                               float* __restrict__ out){
  const int t = threadIdx.x;
  const int a = blockIdx.x*256 + t;
  float mm = -INFINITY;
  #pragma unroll 8
  for (int sp = 0; sp < NSPLIT; sp++)
    mm = fmaxf(mm, partM[(size_t)sp*WB + a]);
  float ll = 0.f, pp = 0.f;
  #pragma unroll 8
  for (int sp = 0; sp < NSPLIT; sp++){
    ll = fmaf(partL[(size_t)sp*WB + a], EXP2(partM[(size_t)sp*WB + a] - mm), ll);
    pp += partPS[(size_t)sp*WB + a];
  }
  float lse2 = mm + LOG2(ll);             // log2 units
  int lab = labels[a];
  int np = cnt[lab] - 1;
  float loss = 0.f, val = 0.f;
  if (np > 0){ loss = LN2F*(lse2 - pp/(float)np); val = 1.f; }
  #pragma unroll
  for (int off = 32; off > 0; off >>= 1){
    loss += __shfl_down(loss, off);
    val  += __shfl_down(val,  off);
  }
  __shared__ float sl[4], sv[4];
  int wv = t>>6, lane = t&63;
  if (lane == 0){ sl[wv] = loss; sv[wv] = val; }
  __syncthreads();
  if (t == 0){
    atomicAdd(accf, sl[0]+sl[1]+sl[2]+sl[3]);
    atomicAdd(accn, (int)(sv[0]+sv[1]+sv[2]+sv[3] + 0.5f));
    __threadfence();
    int tk = atomicAdd(ticket, 1);
    if (tk == 31){                         // last block finalizes
      float f = atomicAdd(accf, 0.f);
      int   n = atomicAdd(accn, 0);
      out[0] = f / (float)max(n, 1);
    }
  }
}

extern "C" void kernel_launch(void* const* d_in, const int* in_sizes, int n_in,
                              void* d_out, int out_size, void* d_ws, size_t ws_size,
                              hipStream_t stream){
  const float* z = (const float*)d_in[0];
  const int* labels = (const int*)d_in[1];
  char* ws = (char*)d_ws;
  unsigned short* zbf = (unsigned short*)(ws + WS_ZBF);
  int*      cnt    = (int*)(ws + WS_CNT);
  float*    accf   = (float*)(ws + WS_ACC);
  int*      accn   = (int*)(ws + WS_ACC + 4);
  int*      ticket = (int*)(ws + WS_ACC + 8);
  unsigned* labu8  = (unsigned*)(ws + WS_LAB);
  float*    partM  = (float*)(ws + WS_PM);
  float*    partL  = (float*)(ws + WS_PL);
  float*    partPS = (float*)(ws + WS_PP);
  float* out = (float*)d_out;

  hipMemsetAsync(ws + WS_CNT, 0, 512 + 16, stream);   // cnt + acc/ticket
  hipLaunchKernelGGL(k_prep,  dim3(520), dim3(256), 0, stream,
                     z, labels, zbf, labu8, cnt);
  hipLaunchKernelGGL(k_lse,   dim3(512), dim3(256), 0, stream,
                     zbf, labels, labu8, partM, partL, partPS);
  hipLaunchKernelGGL(k_final, dim3(32),  dim3(256), 0, stream,
                     labels, cnt, partM, partL, partPS, accf, accn, ticket, out);
}

// Round 16
// 50.511 us; speedup vs baseline: 1.7504x; 1.0718x over previous
//
#include <hip/hip_runtime.h>
#include <hip/hip_bf16.h>

#define WB 8192
#define WD 128
#define WC 100
#define NSPLIT 16
#define JSPL (WB/NSPLIT)   // 512 j per split
#define NTT (JSPL/16)      // 32 j-steps of 16 rows
#define NPH (NTT/4)        // 8 phases of 4 steps (64 rows)
#define PITCH 272          // 256B row + 16B pad (bank decorrelation)

typedef __attribute__((ext_vector_type(8))) short short8v;
typedef __attribute__((ext_vector_type(4))) float float4v;

#define SQS 3.798282f                 // sqrt((1/TAU)/ln2): fold scale into bf16 z
#define LN2F 0.69314718055994531f

#define EXP2(x) __builtin_amdgcn_exp2f(x)
#define LOG2(x) __builtin_amdgcn_logf(x)

// ---- workspace layout (bytes) ----
#define WS_ZBF   0u          // bf16 z (pre-scaled): 2097152
#define WS_CNTP  2097152u    // cntpart[8][128] int = 4096 (plain stores, no zeroing)
#define WS_ACC   2101248u    // accf, accn, ticket, pad = 16 (zeroed by k_prep)
#define WS_LAB   2101264u    // labu8[8192] = 8192
#define WS_PM    2109456u    // partM[16][8192] f32 = 524288
#define WS_PL    2633744u    // partL[16][8192] f32 = 524288
#define WS_PP    3158032u    // partPS[16][8192] f32 = 524288 (end 3682320)

__device__ __forceinline__ unsigned short f2bf(float x){
  unsigned u = __float_as_uint(x);
  u += 0x7fffu + ((u>>16)&1u);      // RNE
  return (unsigned short)(u>>16);
}

// blocks 0..511: convert+prescale z->bf16; 512..519: labels->u8 + histogram slab.
// block 512 thread 0 also zeroes acc/ticket (read only by later kernels).
__global__ __launch_bounds__(256) void k_prep(const float* __restrict__ z,
                                              const int* __restrict__ labels,
                                              unsigned short* __restrict__ zbf,
                                              unsigned* __restrict__ labu8,
                                              int* __restrict__ cntpart,
                                              float* accf, int* accn, int* ticket){
  const int bid = blockIdx.x, t = threadIdx.x;
  if (bid < 512){
    int idx = bid*256 + t;
    const float4* zi = (const float4*)z;
    float4 a = zi[idx*2], b = zi[idx*2+1];
    uint4 o;
    o.x = (unsigned)f2bf(a.x*SQS) | ((unsigned)f2bf(a.y*SQS)<<16);
    o.y = (unsigned)f2bf(a.z*SQS) | ((unsigned)f2bf(a.w*SQS)<<16);
    o.z = (unsigned)f2bf(b.x*SQS) | ((unsigned)f2bf(b.y*SQS)<<16);
    o.w = (unsigned)f2bf(b.z*SQS) | ((unsigned)f2bf(b.w*SQS)<<16);
    ((uint4*)zbf)[idx] = o;
    return;
  }
  __shared__ int hist[128];
  const int cb = bid - 512;              // 8 blocks x 1024 labels
  if (t < 128) hist[t] = 0;
  if (bid == 512 && t == 0){ accf[0] = 0.f; accn[0] = 0; ticket[0] = 0; }
  __syncthreads();
  {  // pack 4 labels -> u32, and histogram
    int i = cb*1024 + t*4;
    int4 l4 = *(const int4*)(labels + i);
    labu8[cb*256 + t] = (unsigned)l4.x | ((unsigned)l4.y<<8)
                      | ((unsigned)l4.z<<16) | ((unsigned)l4.w<<24);
    atomicAdd(&hist[l4.x], 1); atomicAdd(&hist[l4.y], 1);
    atomicAdd(&hist[l4.z], 1); atomicAdd(&hist[l4.w], 1);
  }
  __syncthreads();
  if (t < 128) cntpart[cb*128 + t] = hist[t];   // plain store, no global zero
}

// 512 blocks x 256 (4 waves). Block shares one split; A-tile staged once per
// block into LDS in 64-row double-buffered phases (4x VMEM cut vs per-wave).
__global__ __launch_bounds__(256) void k_lse(const unsigned short* __restrict__ zbf,
                                             const int* __restrict__ labels,
                                             const unsigned* __restrict__ labu8,
                                             float* __restrict__ partM,
                                             float* __restrict__ partL,
                                             float* __restrict__ partPS){
  __shared__ __align__(16) unsigned char atile[2][64*PITCH];  // 2 x 17 KB
  __shared__ unsigned ldslab[JSPL/4];      // 128 words = this split's 512 labels
  const int t = threadIdx.x, wv = t>>6, lane = t&63;
  const int bid = blockIdx.x;
  const int xcd = bid & 7, chunk = bid >> 3;
  const int split = (xcd<<1) | (chunk & 1);          // XCD owns 2 j-windows
  const int ablk  = ((chunk>>1)<<2) | wv;            // 0..127
  const int awave = ablk*64;
  const int j0 = split*JSPL;
  const int lg = lane>>4, ln = lane&15;
  const bool DIAG = ((awave >> 9) == split);

  if (t < JSPL/4) ldslab[t] = labu8[(j0>>2) + t];

  // anchor B-fragments: B[k][n]; lane: n=ln, k=kk*32+lg*8+e
  short8v bf[4][4];
  int labA[4];
  #pragma unroll
  for (int ss = 0; ss < 4; ss++){
    const unsigned short* zr = zbf + (size_t)(awave + ss*16 + ln)*WD;
    #pragma unroll
    for (int kk = 0; kk < 4; kk++)
      bf[ss][kk] = *(const short8v*)(zr + kk*32 + lg*8);
    labA[ss] = labels[awave + ss*16 + ln];
  }

  float m[4], l[4], ps[4];
  #pragma unroll
  for (int ss = 0; ss < 4; ss++){ m[ss] = -INFINITY; l[ss] = 0.f; ps[ss] = 0.f; }

  // staging: thread t handles row srow0+16q, 16B chunk sck (q=0..3)
  const int srow0 = t>>4, sck = t&15;
  const unsigned short* sb = zbf + (size_t)(j0 + srow0)*WD + sck*8;
  const unsigned swbase = srow0*PITCH + sck*16;

  // prologue: stage phase 0 into buf 0
  {
    uint4 s0 = *(const uint4*)(sb + (size_t)( 0)*WD);
    uint4 s1 = *(const uint4*)(sb + (size_t)(16)*WD);
    uint4 s2 = *(const uint4*)(sb + (size_t)(32)*WD);
    uint4 s3 = *(const uint4*)(sb + (size_t)(48)*WD);
    *(uint4*)&atile[0][swbase +  0*PITCH] = s0;
    *(uint4*)&atile[0][swbase + 16*PITCH] = s1;
    *(uint4*)&atile[0][swbase + 32*PITCH] = s2;
    *(uint4*)&atile[0][swbase + 48*PITCH] = s3;
  }
  __syncthreads();

  for (int ph = 0; ph < NPH; ph++){
    const int cur = ph & 1;
    // T14: issue next phase's global loads NOW; they drain during compute
    uint4 nx0, nx1, nx2, nx3;
    const bool have = (ph+1 < NPH);
    if (have){
      const unsigned short* nb = sb + (size_t)((ph+1)*64)*WD;
      nx0 = *(const uint4*)(nb + (size_t)( 0)*WD);
      nx1 = *(const uint4*)(nb + (size_t)(16)*WD);
      nx2 = *(const uint4*)(nb + (size_t)(32)*WD);
      nx3 = *(const uint4*)(nb + (size_t)(48)*WD);
    }
    #pragma unroll
    for (int s = 0; s < 4; s++){
      const int tt = ph*4 + s;
      const int jb = j0 + tt*16;
      const unsigned lw = ldslab[tt*4 + lg];
      const int b0 = (int)(lw&255u),       b1 = (int)((lw>>8)&255u);
      const int b2 = (int)((lw>>16)&255u), b3 = (int)(lw>>24);
      const int rl = s*16 + ln;
      const unsigned rbase = rl*PITCH + lg*16;
      short8v af0 = *(const short8v*)&atile[cur][rbase +   0];
      short8v af1 = *(const short8v*)&atile[cur][rbase +  64];
      short8v af2 = *(const short8v*)&atile[cur][rbase + 128];
      short8v af3 = *(const short8v*)&atile[cur][rbase + 192];
      #pragma unroll
      for (int ss = 0; ss < 4; ss++){
        float4v acc = {0.f,0.f,0.f,0.f};
        acc = __builtin_amdgcn_mfma_f32_16x16x32_bf16(af0, bf[ss][0], acc, 0,0,0);
        acc = __builtin_amdgcn_mfma_f32_16x16x32_bf16(af1, bf[ss][1], acc, 0,0,0);
        acc = __builtin_amdgcn_mfma_f32_16x16x32_bf16(af2, bf[ss][2], acc, 0,0,0);
        acc = __builtin_amdgcn_mfma_f32_16x16x32_bf16(af3, bf[ss][3], acc, 0,0,0);
        float v0 = acc[0], v1 = acc[1], v2 = acc[2], v3 = acc[3];
        ps[ss] += ((b0==labA[ss]) ? v0 : 0.f) + ((b1==labA[ss]) ? v1 : 0.f)
                + ((b2==labA[ss]) ? v2 : 0.f) + ((b3==labA[ss]) ? v3 : 0.f);
        if (DIAG && jb == awave + ss*16){   // wave-uniform; self always matches
          const int r0 = lg*4;
          if (r0+0 == ln){ ps[ss] -= v0; v0 = -INFINITY; }
          if (r0+1 == ln){ ps[ss] -= v1; v1 = -INFINITY; }
          if (r0+2 == ln){ ps[ss] -= v2; v2 = -INFINITY; }
          if (r0+3 == ln){ ps[ss] -= v3; v3 = -INFINITY; }
        }
        float tmax = fmaxf(fmaxf(v0,v1), fmaxf(v2,v3));
        float mn = fmaxf(m[ss], tmax);
        l[ss] = l[ss]*EXP2(m[ss]-mn)
              + ((EXP2(v0-mn) + EXP2(v1-mn)) + (EXP2(v2-mn) + EXP2(v3-mn)));
        m[ss] = mn;
      }
    }
    if (have){
      *(uint4*)&atile[cur^1][swbase +  0*PITCH] = nx0;
      *(uint4*)&atile[cur^1][swbase + 16*PITCH] = nx1;
      *(uint4*)&atile[cur^1][swbase + 32*PITCH] = nx2;
      *(uint4*)&atile[cur^1][swbase + 48*PITCH] = nx3;
    }
    __syncthreads();
  }

  // combine lanes {x^16, x^32} (same anchor, different j-row groups)
  #pragma unroll
  for (int ss = 0; ss < 4; ss++){
    float mm = m[ss], ll = l[ss], pp = ps[ss];
    #pragma unroll
    for (int off = 16; off < 64; off <<= 1){
      float mo = __shfl_xor(mm, off);
      float lo = __shfl_xor(ll, off);
      float M = fmaxf(mm, mo);
      ll = ll*EXP2(mm-M) + lo*EXP2(mo-M);
      mm = M;
      pp += __shfl_xor(pp, off);
    }
    if (lane < 16){
      size_t o = (size_t)split*WB + awave + ss*16 + lane;
      partM[o] = mm; partL[o] = ll; partPS[o] = pp;
    }
  }
}

// 32 blocks x 256 threads: one anchor per thread.
__global__ __launch_bounds__(256) void k_final(const int* __restrict__ labels,
                                               const int* __restrict__ cntpart,
                                               const float* __restrict__ partM,
                                               const float* __restrict__ partL,
                                               const float* __restrict__ partPS,
                                               float* accf, int* accn, int* ticket,
                                               float* __restrict__ out){
  const int t = threadIdx.x;
  const int a = blockIdx.x*256 + t;
  float mm = -INFINITY;
  #pragma unroll 8
  for (int sp = 0; sp < NSPLIT; sp++)
    mm = fmaxf(mm, partM[(size_t)sp*WB + a]);
  float ll = 0.f, pp = 0.f;
  #pragma unroll 8
  for (int sp = 0; sp < NSPLIT; sp++){
    ll = fmaf(partL[(size_t)sp*WB + a], EXP2(partM[(size_t)sp*WB + a] - mm), ll);
    pp += partPS[(size_t)sp*WB + a];
  }
  float lse2 = mm + LOG2(ll);             // log2 units
  int lab = labels[a];
  int c = 0;
  #pragma unroll
  for (int b = 0; b < 8; b++) c += cntpart[b*128 + lab];
  int np = c - 1;
  float loss = 0.f, val = 0.f;
  if (np > 0){ loss = LN2F*(lse2 - pp/(float)np); val = 1.f; }
  #pragma unroll
  for (int off = 32; off > 0; off >>= 1){
    loss += __shfl_down(loss, off);
    val  += __shfl_down(val,  off);
  }
  __shared__ float sl[4], sv[4];
  int wv = t>>6, lane = t&63;
  if (lane == 0){ sl[wv] = loss; sv[wv] = val; }
  __syncthreads();
  if (t == 0){
    atomicAdd(accf, sl[0]+sl[1]+sl[2]+sl[3]);
    atomicAdd(accn, (int)(sv[0]+sv[1]+sv[2]+sv[3] + 0.5f));
    __threadfence();
    int tk = atomicAdd(ticket, 1);
    if (tk == 31){                         // last block finalizes
      float f = atomicAdd(accf, 0.f);
      int   n = atomicAdd(accn, 0);
      out[0] = f / (float)max(n, 1);
    }
  }
}

extern "C" void kernel_launch(void* const* d_in, const int* in_sizes, int n_in,
                              void* d_out, int out_size, void* d_ws, size_t ws_size,
                              hipStream_t stream){
  const float* z = (const float*)d_in[0];
  const int* labels = (const int*)d_in[1];
  char* ws = (char*)d_ws;
  unsigned short* zbf = (unsigned short*)(ws + WS_ZBF);
  int*      cntp   = (int*)(ws + WS_CNTP);
  float*    accf   = (float*)(ws + WS_ACC);
  int*      accn   = (int*)(ws + WS_ACC + 4);
  int*      ticket = (int*)(ws + WS_ACC + 8);
  unsigned* labu8  = (unsigned*)(ws + WS_LAB);
  float*    partM  = (float*)(ws + WS_PM);
  float*    partL  = (float*)(ws + WS_PL);
  float*    partPS = (float*)(ws + WS_PP);
  float* out = (float*)d_out;

  hipLaunchKernelGGL(k_prep,  dim3(520), dim3(256), 0, stream,
                     z, labels, zbf, labu8, cntp, accf, accn, ticket);
  hipLaunchKernelGGL(k_lse,   dim3(512), dim3(256), 0, stream,
                     zbf, labels, labu8, partM, partL, partPS);
  hipLaunchKernelGGL(k_final, dim3(32),  dim3(256), 0, stream,
                     labels, cntp, partM, partL, partPS, accf, accn, ticket, out);
}